// Round 2
// baseline (318.963 us; speedup 1.0000x reference)
//
#include <hip/hip_runtime.h>
#include <cstdint>
#include <cstddef>

#define NB  8
#define NC  128
#define NHW 36864

// workspace layout (floats)
#define GOFF  0         // 8*128*128
#define SOFF  131072    // 8*128
#define AOFF  132096    // 8*128*128
#define TOFF  263168    // 8*128
#define ROFF  264192    // 8*128*128
#define MOFF  395264    // 8*128*128
#define CVOFF 526336    // 8*128

typedef __attribute__((ext_vector_type(8))) short short8;
typedef __attribute__((ext_vector_type(4))) float f32x4;

static __device__ __forceinline__ f32x4 zero4(){ f32x4 v = {0.f,0.f,0.f,0.f}; return v; }

static __device__ __forceinline__ short f2bf(float f){
    union { float f; uint32_t u; } c; c.f = f;
    uint32_t r = c.u + 0x7fffu + ((c.u >> 16) & 1u);   // RNE truncate to bf16
    return (short)(r >> 16);
}
static __device__ __forceinline__ float bf2f(short h){
    union { uint32_t u; float f; } c; c.u = ((uint32_t)(uint16_t)h) << 16;
    return c.f;
}

static __device__ __forceinline__ void load_conv8(const float* __restrict__ p,
                                                  short8& h, short8& l, float& ssum){
    f32x4 v0 = *(const f32x4*)p;
    f32x4 v1 = *(const f32x4*)(p + 4);
#pragma unroll
    for (int j=0;j<4;j++){
        float f0 = v0[j], f1 = v1[j];
        short h0 = f2bf(f0), h1 = f2bf(f1);
        h[j] = h0; h[4+j] = h1;
        l[j]   = f2bf(f0 - bf2f(h0));
        l[4+j] = f2bf(f1 - bf2f(h1));
        ssum += f0 + f1;
    }
}

// ---- K1: per-batch G = sum_n x x^T (bf16 hi/lo split MFMA), s = sum_n x ----
__global__ __launch_bounds__(256) void k_gram(const float* __restrict__ x,
                                              float* __restrict__ G,
                                              float* __restrict__ svec){
    const int b     = blockIdx.y;
    const int chunk = blockIdx.x;            // 64 chunks * 576 n
    const int tid  = threadIdx.x;
    const int wid  = tid >> 6;
    const int lane = tid & 63;
    const int l16  = lane & 15;
    const int lg   = lane >> 4;
    const int rg0 = wid*2, rg1 = wid*2 + 1;  // this wave's row-groups

    f32x4 acc[2][8];
#pragma unroll
    for (int p=0;p<2;p++)
#pragma unroll
      for (int g=0;g<8;g++) acc[p][g] = zero4();
    float ssum[8];
#pragma unroll
    for (int g=0;g<8;g++) ssum[g]=0.f;

    const float* xb = x + (size_t)b*NC*NHW;
    for (int s=0;s<18;s++){
        const int n0 = chunk*576 + s*32 + lg*8;
        short8 hi[8], lo[8];
        float dummy = 0.f;
#pragma unroll
        for (int g=0; g<8; g++){
            float sacc = 0.f;
            load_conv8(xb + (size_t)(g*16 + l16)*NHW + n0, hi[g], lo[g], sacc);
            if (wid == 0) ssum[g] += sacc;
        }
        // this wave's A-fragments (named vars: avoid runtime-indexed arrays -> scratch)
        short8 a0h, a0l, a1h, a1l;
        load_conv8(xb + (size_t)(rg0*16 + l16)*NHW + n0, a0h, a0l, dummy);
        load_conv8(xb + (size_t)(rg1*16 + l16)*NHW + n0, a1h, a1l, dummy);
#pragma unroll
        for (int g=0; g<8; g++){
            acc[0][g] = __builtin_amdgcn_mfma_f32_16x16x32_bf16(a0h, hi[g], acc[0][g], 0,0,0);
            acc[0][g] = __builtin_amdgcn_mfma_f32_16x16x32_bf16(a0h, lo[g], acc[0][g], 0,0,0);
            acc[0][g] = __builtin_amdgcn_mfma_f32_16x16x32_bf16(a0l, hi[g], acc[0][g], 0,0,0);
            acc[1][g] = __builtin_amdgcn_mfma_f32_16x16x32_bf16(a1h, hi[g], acc[1][g], 0,0,0);
            acc[1][g] = __builtin_amdgcn_mfma_f32_16x16x32_bf16(a1h, lo[g], acc[1][g], 0,0,0);
            acc[1][g] = __builtin_amdgcn_mfma_f32_16x16x32_bf16(a1l, hi[g], acc[1][g], 0,0,0);
        }
    }
    // C/D layout (verified): col = lane&15, row = (lane>>4)*4 + reg
#pragma unroll
    for (int p=0;p<2;p++){
        const int rg = wid*2 + p;
#pragma unroll
        for (int g=0;g<8;g++){
#pragma unroll
            for (int r=0;r<4;r++){
                const int row = rg*16 + lg*4 + r;
                const int col = g*16 + l16;
                atomicAdd(&G[((size_t)b*NC + row)*NC + col], acc[p][g][r]);
            }
        }
    }
    if (wid==0){
#pragma unroll
        for (int g=0;g<8;g++){
            float v = ssum[g];
            v += __shfl_xor(v, 16);
            v += __shfl_xor(v, 32);
            if (lane < 16) atomicAdd(&svec[b*NC + g*16 + lane], v);
        }
    }
}

// ---- K2: energy strip = Wq G Wk^T + rank-1 bias terms; softmax -> A; t = A bv ----
__global__ __launch_bounds__(256) void k_energy(const float* __restrict__ G,
        const float* __restrict__ svec,
        const float* __restrict__ Wq, const float* __restrict__ bq,
        const float* __restrict__ Wk, const float* __restrict__ bk,
        const float* __restrict__ bv,
        float* __restrict__ A, float* __restrict__ tvec){
    const int b  = blockIdx.y;
    const int d0 = blockIdx.x * 16;
    const int tid = threadIdx.x;
    const int d  = tid & 15;
    const int ec = tid >> 4;

    __shared__ float Ps[16][128];
    __shared__ float Es[16][128];
    __shared__ float red[16][16];
    __shared__ float rowmax[16];
    __shared__ float rowsum[16];
    __shared__ float qs[16];

    const float* Wqrow = Wq + (size_t)(d0 + d)*NC;
    const float* sb = svec + b*NC;
    // P[d][c] = sum_c' Wq[d0+d,c'] * G[c,c']   (G symmetric -> row-major stream)
#pragma unroll
    for (int i=0;i<8;i++){
        const int c = ec*8 + i;
        const float* Grow = G + ((size_t)b*NC + c)*NC;
        float a = 0.f;
        for (int c4=0;c4<32;c4++){
            f32x4 g4 = *(const f32x4*)(Grow + c4*4);
            f32x4 w4 = *(const f32x4*)(Wqrow + c4*4);
            a += g4[0]*w4[0] + g4[1]*w4[1] + g4[2]*w4[2] + g4[3]*w4[3];
        }
        Ps[d][c] = a;
    }
    if (ec == 0){
        float a = 0.f;
        for (int c4=0;c4<32;c4++){
            f32x4 w4 = *(const f32x4*)(Wqrow + c4*4);
            f32x4 s4 = *(const f32x4*)(sb + c4*4);
            a += w4[0]*s4[0] + w4[1]*s4[1] + w4[2]*s4[2] + w4[3]*s4[3];
        }
        qs[d] = a;
    }
    __syncthreads();
    const float bqd = bq[d0+d];
#pragma unroll
    for (int i=0;i<8;i++){
        const int e = ec*8 + i;
        const float* Wkrow = Wk + (size_t)e*NC;
        float ea = 0.f, ks = 0.f;
        for (int c4=0;c4<32;c4++){
            f32x4 w4 = *(const f32x4*)(Wkrow + c4*4);
            f32x4 p4 = *(const f32x4*)(&Ps[d][c4*4]);
            f32x4 s4 = *(const f32x4*)(sb + c4*4);
            ea += w4[0]*p4[0]+w4[1]*p4[1]+w4[2]*p4[2]+w4[3]*p4[3];
            ks += w4[0]*s4[0]+w4[1]*s4[1]+w4[2]*s4[2]+w4[3]*s4[3];
        }
        const float bke = bk[e];
        Es[d][e] = ea + bke*qs[d] + bqd*ks + (float)NHW*bqd*bke;
    }
    // softmax over row d: 16 threads per row, 8 entries each
    float m8 = -3.4e38f;
#pragma unroll
    for (int i=0;i<8;i++) m8 = fmaxf(m8, Es[d][ec*8+i]);
    red[d][ec] = m8;
    __syncthreads();
    if (tid < 16){
        float m = red[tid][0];
        for (int j=1;j<16;j++) m = fmaxf(m, red[tid][j]);
        rowmax[tid] = m;
    }
    __syncthreads();
    const float rm = rowmax[d];
    float s8 = 0.f;
#pragma unroll
    for (int i=0;i<8;i++){
        float ex = expf(Es[d][ec*8+i] - rm);
        Es[d][ec*8+i] = ex;
        s8 += ex;
    }
    red[d][ec] = s8;
    __syncthreads();
    if (tid < 16){
        float sm = 0.f;
        for (int j=0;j<16;j++) sm += red[tid][j];
        rowsum[tid] = sm;
    }
    __syncthreads();
    const float inv = 1.f / rowsum[d];
    float ta = 0.f;
    float* Arow = A + ((size_t)b*NC + d0 + d)*NC;
#pragma unroll
    for (int i=0;i<8;i++){
        const int e = ec*8 + i;
        float av = Es[d][e] * inv;
        Arow[e] = av;
        ta += av * bv[e];
    }
    red[d][ec] = ta;
    __syncthreads();
    if (tid < 16){
        float sm = 0.f;
        for (int j=0;j<16;j++) sm += red[tid][j];
        tvec[b*NC + d0 + tid] = sm;
    }
}

// ---- K3: R = A * Wv ----
__global__ __launch_bounds__(256) void k_av(const float* __restrict__ A,
        const float* __restrict__ Wv, float* __restrict__ R){
    const int b = blockIdx.y, d0 = blockIdx.x*16;
    const int tid = threadIdx.x, d = tid&15, cc = tid>>4;
    const int c0 = cc*8;
    const float* Arow = A + ((size_t)b*NC + d0 + d)*NC;
    float a[8];
#pragma unroll
    for (int i=0;i<8;i++) a[i]=0.f;
    for (int e=0;e<NC;e++){
        const float av = Arow[e];
        const float* w = Wv + (size_t)e*NC + c0;
        f32x4 w0 = *(const f32x4*)w;
        f32x4 w1 = *(const f32x4*)(w+4);
        a[0]+=av*w0[0]; a[1]+=av*w0[1]; a[2]+=av*w0[2]; a[3]+=av*w0[3];
        a[4]+=av*w1[0]; a[5]+=av*w1[1]; a[6]+=av*w1[2]; a[7]+=av*w1[3];
    }
    float* Rrow = R + ((size_t)b*NC + d0 + d)*NC + c0;
#pragma unroll
    for (int i=0;i<8;i++) Rrow[i] = a[i];
}

// ---- K4: M = Wo * R ; cvec = Wo * t + bo ----
__global__ __launch_bounds__(256) void k_om(const float* __restrict__ R,
        const float* __restrict__ Wo, const float* __restrict__ bo,
        const float* __restrict__ tvec, float* __restrict__ M, float* __restrict__ cvec){
    const int b = blockIdx.y, o0 = blockIdx.x*16;
    const int tid = threadIdx.x, o = tid&15, cc = tid>>4;
    const int c0 = cc*8;
    const float* Worow = Wo + (size_t)(o0+o)*NC;
    const float* tb = tvec + b*NC;
    float a[8];
#pragma unroll
    for (int i=0;i<8;i++) a[i]=0.f;
    float cv = 0.f;
    for (int dd=0; dd<NC; dd++){
        const float wv = Worow[dd];
        const float* r = R + ((size_t)b*NC + dd)*NC + c0;
        f32x4 r0 = *(const f32x4*)r;
        f32x4 r1 = *(const f32x4*)(r+4);
        a[0]+=wv*r0[0]; a[1]+=wv*r0[1]; a[2]+=wv*r0[2]; a[3]+=wv*r0[3];
        a[4]+=wv*r1[0]; a[5]+=wv*r1[1]; a[6]+=wv*r1[2]; a[7]+=wv*r1[3];
        cv += wv*tb[dd];
    }
    float* Mrow = M + ((size_t)b*NC + o0+o)*NC + c0;
#pragma unroll
    for (int i=0;i<8;i++) Mrow[i] = a[i];
    if (cc == 0) cvec[b*NC + o0 + o] = cv + bo[o0+o];
}

// ---- K5: out = gamma*(M x + cvec) + x  (bf16 MFMA over m) ----
__global__ __launch_bounds__(256) void k_final(const float* __restrict__ x,
        const float* __restrict__ M, const float* __restrict__ cvec,
        const float* __restrict__ gamma, float* __restrict__ out){
    const int b  = blockIdx.y;
    const int n0 = blockIdx.x * 128;
    const int tid = threadIdx.x;
    const int wid = tid >> 6, lane = tid & 63;
    const int l16 = lane & 15, lg = lane >> 4;

    __shared__ short Xs[128][130];   // stride 130: B-frag reads stay <=2-way bank aliased

    {   // stage x[b,:,n0:n0+128] as bf16
        const int nof = (tid & 31)*4;
        const int mb  = tid >> 5;
        const float* xb = x + (size_t)b*NC*NHW + n0 + nof;
#pragma unroll
        for (int i=0;i<16;i++){
            const int m = mb + i*8;
            f32x4 v = *(const f32x4*)(xb + (size_t)m*NHW);
            uint32_t p0 = ((uint32_t)(uint16_t)f2bf(v[1]) << 16) | (uint32_t)(uint16_t)f2bf(v[0]);
            uint32_t p1 = ((uint32_t)(uint16_t)f2bf(v[3]) << 16) | (uint32_t)(uint16_t)f2bf(v[2]);
            uint32_t* dst = (uint32_t*)&Xs[m][nof];
            dst[0] = p0; dst[1] = p1;
        }
    }
    // load all M fragments into registers (compile-time indexed)
    short8 af[8][4];
#pragma unroll
    for (int cg=0;cg<8;cg++)
#pragma unroll
      for (int mg=0;mg<4;mg++){
        const float* p = M + ((size_t)b*NC + cg*16 + l16)*NC + mg*32 + lg*8;
        f32x4 v0 = *(const f32x4*)p;
        f32x4 v1 = *(const f32x4*)(p+4);
        short8 h;
#pragma unroll
        for (int j=0;j<4;j++){ h[j]=f2bf(v0[j]); h[4+j]=f2bf(v1[j]); }
        af[cg][mg]=h;
      }
    __syncthreads();

    f32x4 acc[2][8];
#pragma unroll
    for (int t=0;t<2;t++)
#pragma unroll
      for (int g=0;g<8;g++) acc[t][g]=zero4();

#pragma unroll
    for (int mg=0;mg<4;mg++){
        short8 bf0, bf1;
        const int mb2 = mg*32 + lg*8;
        const int nA = wid*32 + l16;
        const int nB = wid*32 + 16 + l16;
#pragma unroll
        for (int j=0;j<8;j++){
            bf0[j] = Xs[mb2+j][nA];
            bf1[j] = Xs[mb2+j][nB];
        }
#pragma unroll
        for (int cg=0;cg<8;cg++){
            acc[0][cg] = __builtin_amdgcn_mfma_f32_16x16x32_bf16(af[cg][mg], bf0, acc[0][cg], 0,0,0);
            acc[1][cg] = __builtin_amdgcn_mfma_f32_16x16x32_bf16(af[cg][mg], bf1, acc[1][cg], 0,0,0);
        }
    }

    const float gm = gamma[0];
#pragma unroll
    for (int t=0;t<2;t++){
        const int n = n0 + wid*32 + t*16 + l16;
#pragma unroll
        for (int cg=0;cg<8;cg++){
#pragma unroll
            for (int r=0;r<4;r++){
                const int c = cg*16 + lg*4 + r;
                const size_t idx = ((size_t)b*NC + c)*NHW + n;
                out[idx] = gm*(acc[t][cg][r] + cvec[b*NC + c]) + x[idx];
            }
        }
    }
}

extern "C" void kernel_launch(void* const* d_in, const int* in_sizes, int n_in,
                              void* d_out, int out_size, void* d_ws, size_t ws_size,
                              hipStream_t stream){
    const float* x     = (const float*)d_in[0];
    const float* Wq    = (const float*)d_in[1];
    const float* bq    = (const float*)d_in[2];
    const float* Wk    = (const float*)d_in[3];
    const float* bk    = (const float*)d_in[4];
    const float* Wv    = (const float*)d_in[5];
    const float* bv    = (const float*)d_in[6];
    const float* Wo    = (const float*)d_in[7];
    const float* bo    = (const float*)d_in[8];
    const float* gamma = (const float*)d_in[9];
    float* out = (float*)d_out;

    float* w  = (float*)d_ws;
    float* G  = w + GOFF;
    float* S  = w + SOFF;
    float* A  = w + AOFF;
    float* T  = w + TOFF;
    float* R  = w + ROFF;
    float* Mm = w + MOFF;
    float* CV = w + CVOFF;

    // zero accumulation targets (G and s are atomically accumulated)
    hipMemsetAsync(G, 0, (size_t)(131072 + 1024)*sizeof(float), stream);

    k_gram  <<<dim3(64, NB), 256, 0, stream>>>(x, G, S);
    k_energy<<<dim3(8,  NB), 256, 0, stream>>>(G, S, Wq, bq, Wk, bk, bv, A, T);
    k_av    <<<dim3(8,  NB), 256, 0, stream>>>(A, Wv, R);
    k_om    <<<dim3(8,  NB), 256, 0, stream>>>(R, Wo, bo, T, Mm, CV);
    k_final <<<dim3(288,NB), 256, 0, stream>>>(x, Mm, CV, gamma, out);
}

// Round 3
// 279.893 us; speedup vs baseline: 1.1396x; 1.1396x over previous
//
#include <hip/hip_runtime.h>
#include <cstdint>
#include <cstddef>

#define NB  8
#define NC  128
#define NHW 36864

// workspace layout (float offsets)
#define GOFF  0         // 8*128*128
#define SOFF  131072    // 8*128
#define TOFF  132096    // 8*128
#define ROFF  133120    // 8*128*128
#define CVOFF 264192    // 8*128
#define MBOFF 265216    // 131072 shorts (bf16 M fragments) = 65536 floats

typedef __attribute__((ext_vector_type(8))) short short8;
typedef __attribute__((ext_vector_type(4))) float f32x4;

static __device__ __forceinline__ f32x4 zero4(){ f32x4 v = {0.f,0.f,0.f,0.f}; return v; }

// float -> bf16 bits via native __bf16 (compiler fuses pairs into v_cvt_pk_bf16_f32)
static __device__ __forceinline__ short bfbits(float f){
    union { __bf16 b; short s; } u; u.b = (__bf16)f; return u.s;
}
// hi/lo split: h = bf16(f), l = bf16(f - float(h))
static __device__ __forceinline__ void cv2(float f, short& hb, short& lb){
    union { __bf16 b; short s; } u;
    u.b = (__bf16)f; hb = u.s;
    float hf = (float)u.b;
    u.b = (__bf16)(f - hf); lb = u.s;
}

// load 8 consecutive floats, produce hi/lo bf16 fragments; returns element sum
static __device__ __forceinline__ float load_conv8(const float* __restrict__ p,
                                                   short8& h, short8& l){
    f32x4 v0 = *(const f32x4*)p;
    f32x4 v1 = *(const f32x4*)(p + 4);
    float ss = 0.f;
#pragma unroll
    for (int j=0;j<4;j++){
        float f0 = v0[j], f1 = v1[j];
        short hb, lb;
        cv2(f0, hb, lb); h[j]   = hb; l[j]   = lb;
        cv2(f1, hb, lb); h[4+j] = hb; l[4+j] = lb;
        ss += f0 + f1;
    }
    return ss;
}

// ---- K1: per-batch G = sum_n x x^T (bf16 hi/lo split MFMA), s = sum_n x ----
template<int W>
static __device__ __forceinline__ void gram_work(const float* __restrict__ xb,
        float* __restrict__ Gb, float* __restrict__ sb,
        const int chunk, const int lane){
    const int l16 = lane & 15, lgi = lane >> 4;
    constexpr int W2 = 2*W;

    f32x4 acc[2][8];
#pragma unroll
    for (int p=0;p<2;p++)
#pragma unroll
      for (int g=0;g<8;g++) acc[p][g] = zero4();
    float ssum[8];
#pragma unroll
    for (int g=0;g<8;g++) ssum[g] = 0.f;

    for (int s=0;s<9;s++){
        const int n0 = chunk*288 + s*32 + lgi*8;
        // this wave's A-fragments (rows W2*16.., (W2+1)*16..) — also serve as B rows g=W2,W2+1
        short8 hA0, lA0, hA1, lA1;
        const float sA0 = load_conv8(xb + (size_t)(W2*16     + l16)*NHW + n0, hA0, lA0);
        const float sA1 = load_conv8(xb + (size_t)((W2+1)*16 + l16)*NHW + n0, hA1, lA1);
#pragma unroll
        for (int g=0; g<8; g++){
            short8 hg, lg2;
            float sg;
            if (g == W2)        { hg = hA0; lg2 = lA0; sg = sA0; }
            else if (g == W2+1) { hg = hA1; lg2 = lA1; sg = sA1; }
            else sg = load_conv8(xb + (size_t)(g*16 + l16)*NHW + n0, hg, lg2);
            if (W == 0) ssum[g] += sg;
            acc[0][g] = __builtin_amdgcn_mfma_f32_16x16x32_bf16(hA0, hg,  acc[0][g], 0,0,0);
            acc[0][g] = __builtin_amdgcn_mfma_f32_16x16x32_bf16(hA0, lg2, acc[0][g], 0,0,0);
            acc[0][g] = __builtin_amdgcn_mfma_f32_16x16x32_bf16(lA0, hg,  acc[0][g], 0,0,0);
            acc[1][g] = __builtin_amdgcn_mfma_f32_16x16x32_bf16(hA1, hg,  acc[1][g], 0,0,0);
            acc[1][g] = __builtin_amdgcn_mfma_f32_16x16x32_bf16(hA1, lg2, acc[1][g], 0,0,0);
            acc[1][g] = __builtin_amdgcn_mfma_f32_16x16x32_bf16(lA1, hg,  acc[1][g], 0,0,0);
        }
    }
    // C/D layout (pass-verified): col = lane&15, row = (lane>>4)*4 + reg
#pragma unroll
    for (int p=0;p<2;p++){
        const int rg = W2 + p;
#pragma unroll
        for (int g=0;g<8;g++){
#pragma unroll
            for (int r=0;r<4;r++){
                atomicAdd(&Gb[(size_t)(rg*16 + lgi*4 + r)*NC + g*16 + l16], acc[p][g][r]);
            }
        }
    }
    if (W == 0){
#pragma unroll
        for (int g=0;g<8;g++){
            float v = ssum[g];
            v += __shfl_xor(v, 16);
            v += __shfl_xor(v, 32);
            if (lane < 16) atomicAdd(&sb[g*16 + lane], v);
        }
    }
}

__global__ __launch_bounds__(256) void k_gram(const float* __restrict__ x,
                                              float* __restrict__ G,
                                              float* __restrict__ svec){
    const int b     = blockIdx.y;
    const int chunk = blockIdx.x;          // 128 chunks * 288 n
    const int tid   = threadIdx.x;
    const int wid   = tid >> 6;
    const int lane  = tid & 63;
    const float* xb = x + (size_t)b*NC*NHW;
    float* Gb = G + (size_t)b*NC*NC;
    float* sb = svec + b*NC;
    switch (wid){
        case 0: gram_work<0>(xb, Gb, sb, chunk, lane); break;
        case 1: gram_work<1>(xb, Gb, sb, chunk, lane); break;
        case 2: gram_work<2>(xb, Gb, sb, chunk, lane); break;
        default: gram_work<3>(xb, Gb, sb, chunk, lane); break;
    }
}

// ---- K2: energy = Wq G Wk^T + rank-1 terms; softmax -> A (LDS); t = A bv; R = A Wv ----
__global__ __launch_bounds__(256) void k_energyav(const float* __restrict__ G,
        const float* __restrict__ svec,
        const float* __restrict__ Wq, const float* __restrict__ bq,
        const float* __restrict__ Wk, const float* __restrict__ bk,
        const float* __restrict__ bv, const float* __restrict__ Wv,
        float* __restrict__ R, float* __restrict__ tvec){
    const int b  = blockIdx.y;
    const int d0 = blockIdx.x * 16;
    const int tid = threadIdx.x;
    const int d  = tid & 15;
    const int ec = tid >> 4;

    __shared__ float Ps[16][128];
    __shared__ float Es[16][128];
    __shared__ float red[16][16];
    __shared__ float rowmax[16];
    __shared__ float rowsum[16];
    __shared__ float qs[16];

    const float* Wqrow = Wq + (size_t)(d0 + d)*NC;
    const float* sb = svec + b*NC;
    // P[d][c] = sum_c' Wq[d0+d,c'] * G[c,c']  (G symmetric -> row-major stream)
#pragma unroll
    for (int i=0;i<8;i++){
        const int c = ec*8 + i;
        const float* Grow = G + ((size_t)b*NC + c)*NC;
        float a = 0.f;
        for (int c4=0;c4<32;c4++){
            f32x4 g4 = *(const f32x4*)(Grow + c4*4);
            f32x4 w4 = *(const f32x4*)(Wqrow + c4*4);
            a += g4[0]*w4[0] + g4[1]*w4[1] + g4[2]*w4[2] + g4[3]*w4[3];
        }
        Ps[d][c] = a;
    }
    if (ec == 0){
        float a = 0.f;
        for (int c4=0;c4<32;c4++){
            f32x4 w4 = *(const f32x4*)(Wqrow + c4*4);
            f32x4 s4 = *(const f32x4*)(sb + c4*4);
            a += w4[0]*s4[0] + w4[1]*s4[1] + w4[2]*s4[2] + w4[3]*s4[3];
        }
        qs[d] = a;
    }
    __syncthreads();
    const float bqd = bq[d0+d];
#pragma unroll
    for (int i=0;i<8;i++){
        const int e = ec*8 + i;
        const float* Wkrow = Wk + (size_t)e*NC;
        float ea = 0.f, ks = 0.f;
        for (int c4=0;c4<32;c4++){
            f32x4 w4 = *(const f32x4*)(Wkrow + c4*4);
            f32x4 p4 = *(const f32x4*)(&Ps[d][c4*4]);
            f32x4 s4 = *(const f32x4*)(sb + c4*4);
            ea += w4[0]*p4[0]+w4[1]*p4[1]+w4[2]*p4[2]+w4[3]*p4[3];
            ks += w4[0]*s4[0]+w4[1]*s4[1]+w4[2]*s4[2]+w4[3]*s4[3];
        }
        const float bke = bk[e];
        Es[d][e] = ea + bke*qs[d] + bqd*ks + (float)NHW*bqd*bke;
    }
    // softmax over row d
    float m8 = -3.4e38f;
#pragma unroll
    for (int i=0;i<8;i++) m8 = fmaxf(m8, Es[d][ec*8+i]);
    red[d][ec] = m8;
    __syncthreads();
    if (tid < 16){
        float m = red[tid][0];
        for (int j=1;j<16;j++) m = fmaxf(m, red[tid][j]);
        rowmax[tid] = m;
    }
    __syncthreads();
    const float rm = rowmax[d];
    float s8 = 0.f;
#pragma unroll
    for (int i=0;i<8;i++){
        float ex = expf(Es[d][ec*8+i] - rm);
        Es[d][ec*8+i] = ex;
        s8 += ex;
    }
    red[d][ec] = s8;
    __syncthreads();
    if (tid < 16){
        float sm = 0.f;
        for (int j=0;j<16;j++) sm += red[tid][j];
        rowsum[tid] = sm;
    }
    __syncthreads();
    const float inv = 1.f / rowsum[d];
    float ta = 0.f;
#pragma unroll
    for (int i=0;i<8;i++){
        const int e = ec*8 + i;
        float av = Es[d][e] * inv;
        Es[d][e] = av;               // normalized A kept in LDS
        ta += av * bv[e];
    }
    red[d][ec] = ta;
    __syncthreads();
    if (tid < 16){
        float sm = 0.f;
        for (int j=0;j<16;j++) sm += red[tid][j];
        tvec[b*NC + d0 + tid] = sm;
    }
    // R[d0+d][c0..c0+7] = sum_e A[d][e] * Wv[e][c]
    const int c0 = ec*8;
    float racc[8];
#pragma unroll
    for (int i=0;i<8;i++) racc[i]=0.f;
    for (int e=0;e<NC;e++){
        const float av = Es[d][e];
        const float* wv = Wv + (size_t)e*NC + c0;
        f32x4 w0 = *(const f32x4*)wv;
        f32x4 w1 = *(const f32x4*)(wv+4);
        racc[0]+=av*w0[0]; racc[1]+=av*w0[1]; racc[2]+=av*w0[2]; racc[3]+=av*w0[3];
        racc[4]+=av*w1[0]; racc[5]+=av*w1[1]; racc[6]+=av*w1[2]; racc[7]+=av*w1[3];
    }
    float* Rrow = R + ((size_t)b*NC + d0 + d)*NC + c0;
#pragma unroll
    for (int i=0;i<8;i++) Rrow[i] = racc[i];
}

// ---- K3: M = Wo * R -> bf16 fragment layout Mb; cvec = Wo * t + bo ----
__global__ __launch_bounds__(256) void k_om(const float* __restrict__ R,
        const float* __restrict__ Wo, const float* __restrict__ bo,
        const float* __restrict__ tvec, short* __restrict__ Mb,
        float* __restrict__ cvec){
    const int b = blockIdx.y, o0 = blockIdx.x*16;
    const int tid = threadIdx.x, o = tid&15, cc = tid>>4;
    const int c0 = cc*8;
    const float* Worow = Wo + (size_t)(o0+o)*NC;
    const float* tb = tvec + b*NC;
    float a[8];
#pragma unroll
    for (int i=0;i<8;i++) a[i]=0.f;
    float cv = 0.f;
    for (int dd=0; dd<NC; dd++){
        const float wv = Worow[dd];
        const float* r = R + ((size_t)b*NC + dd)*NC + c0;
        f32x4 r0 = *(const f32x4*)r;
        f32x4 r1 = *(const f32x4*)(r+4);
        a[0]+=wv*r0[0]; a[1]+=wv*r0[1]; a[2]+=wv*r0[2]; a[3]+=wv*r0[3];
        a[4]+=wv*r1[0]; a[5]+=wv*r1[1]; a[6]+=wv*r1[2]; a[7]+=wv*r1[3];
        cv += wv*tb[dd];
    }
    // M[c][m] -> fragment (cg, kstep, lane=lg*16+l16, j):  c=cg*16+l16, m=kstep*32+lg*8+j
    const int cfull = o0 + o;
    const int cg = cfull >> 4, l16v = cfull & 15;
    const int kst = c0 >> 5, lgv = (c0 >> 3) & 3;
    const int lanev = lgv*16 + l16v;
    short8 h;
#pragma unroll
    for (int i=0;i<8;i++) h[i] = bfbits(a[i]);
    *(short8*)(Mb + ((((size_t)b*8 + cg)*4 + kst)*64 + lanev)*8) = h;
    if (cc == 0) cvec[b*NC + o0 + o] = cv + bo[o0+o];
}

// ---- K4: out = gamma*(M x + cvec) + x  — no LDS, x streamed as per-lane dwords ----
__global__ __launch_bounds__(256) void k_final(const float* __restrict__ x,
        const short* __restrict__ Mb, const float* __restrict__ cvec,
        const float* __restrict__ gamma, float* __restrict__ out){
    const int b   = blockIdx.y;
    const int tid = threadIdx.x;
    const int wid = tid >> 6, lane = tid & 63;
    const int l16 = lane & 15, lgi = lane >> 4;
    const int n0w = blockIdx.x*128 + wid*32;

    const float* xb  = x + (size_t)b*NC*NHW;
    const short* Mbb = Mb + (size_t)b*8*4*64*8;

    f32x4 acc[2][8];
#pragma unroll
    for (int t=0;t<2;t++)
#pragma unroll
      for (int g=0;g<8;g++) acc[t][g]=zero4();

#pragma unroll
    for (int ks=0;ks<4;ks++){
        // B-fragments: x[m][n], m = ks*32 + lgi*8 + j, n = n0w + {l16, 16+l16}
        const float* xk = xb + (size_t)(ks*32 + lgi*8)*NHW + n0w;
        short8 bf0, bf1;
#pragma unroll
        for (int j=0;j<8;j++){
            bf0[j] = bfbits(xk[(size_t)j*NHW + l16]);
            bf1[j] = bfbits(xk[(size_t)j*NHW + 16 + l16]);
        }
#pragma unroll
        for (int cg=0;cg<8;cg++){
            short8 a = *(const short8*)(Mbb + (((size_t)cg*4 + ks)*64 + lane)*8);
            acc[0][cg] = __builtin_amdgcn_mfma_f32_16x16x32_bf16(a, bf0, acc[0][cg], 0,0,0);
            acc[1][cg] = __builtin_amdgcn_mfma_f32_16x16x32_bf16(a, bf1, acc[1][cg], 0,0,0);
        }
    }

    const float gm = gamma[0];
#pragma unroll
    for (int t=0;t<2;t++){
        const int n = n0w + t*16 + l16;
#pragma unroll
        for (int cg=0;cg<8;cg++){
#pragma unroll
            for (int r=0;r<4;r++){
                const int c = cg*16 + lgi*4 + r;
                const size_t idx = ((size_t)b*NC + c)*NHW + n;
                out[idx] = gm*(acc[t][cg][r] + cvec[b*NC + c]) + x[idx];
            }
        }
    }
}

extern "C" void kernel_launch(void* const* d_in, const int* in_sizes, int n_in,
                              void* d_out, int out_size, void* d_ws, size_t ws_size,
                              hipStream_t stream){
    const float* x     = (const float*)d_in[0];
    const float* Wq    = (const float*)d_in[1];
    const float* bq    = (const float*)d_in[2];
    const float* Wk    = (const float*)d_in[3];
    const float* bk    = (const float*)d_in[4];
    const float* Wv    = (const float*)d_in[5];
    const float* bv    = (const float*)d_in[6];
    const float* Wo    = (const float*)d_in[7];
    const float* bo    = (const float*)d_in[8];
    const float* gamma = (const float*)d_in[9];
    float* out = (float*)d_out;

    float* w  = (float*)d_ws;
    float* G  = w + GOFF;
    float* S  = w + SOFF;
    float* T  = w + TOFF;
    float* R  = w + ROFF;
    float* CV = w + CVOFF;
    short* Mb = (short*)(w + MBOFF);

    // zero atomic-accumulation targets (G and s)
    hipMemsetAsync(G, 0, (size_t)(131072 + 1024)*sizeof(float), stream);

    k_gram    <<<dim3(128, NB), 256, 0, stream>>>(x, G, S);
    k_energyav<<<dim3(8,   NB), 256, 0, stream>>>(G, S, Wq, bq, Wk, bk, bv, Wv, R, T);
    k_om      <<<dim3(8,   NB), 256, 0, stream>>>(R, Wo, bo, T, Mb, CV);
    k_final   <<<dim3(288, NB), 256, 0, stream>>>(x, Mb, CV, gamma, out);
}

// Round 4
// 216.431 us; speedup vs baseline: 1.4737x; 1.2932x over previous
//
#include <hip/hip_runtime.h>
#include <cstdint>
#include <cstddef>

#define NB  8
#define NC  128
#define NHW 36864

// workspace layout (float offsets)
#define GOFF  0         // 8*128*128
#define SOFF  131072    // 8*128
#define TOFF  132096    // 8*128
#define ROFF  133120    // 8*128*128
#define CVOFF 264192    // 8*128
#define MBOFF 265216    // 131072 shorts (bf16 M fragments) = 65536 floats

typedef __attribute__((ext_vector_type(8))) short short8;
typedef __attribute__((ext_vector_type(4))) float f32x4;

static __device__ __forceinline__ f32x4 zero4(){ f32x4 v = {0.f,0.f,0.f,0.f}; return v; }

// float -> bf16 bits via native __bf16 (compiler emits v_cvt_pk_bf16_f32 pairs)
static __device__ __forceinline__ short bfbits(float f){
    union { __bf16 b; short s; } u; u.b = (__bf16)f; return u.s;
}
// hi/lo split: h = bf16(f), l = bf16(f - float(h))
static __device__ __forceinline__ void cv2(float f, short& hb, short& lb){
    union { __bf16 b; short s; } u;
    u.b = (__bf16)f; hb = u.s;
    float hf = (float)u.b;
    u.b = (__bf16)(f - hf); lb = u.s;
}
// two f32x4 (8 consecutive cols) -> hi/lo short8 fragments; returns sum
static __device__ __forceinline__ float cv8(f32x4 v0, f32x4 v1, short8& h, short8& l){
    float ss = 0.f;
#pragma unroll
    for (int j=0;j<4;j++){
        short hb, lb;
        cv2(v0[j], hb, lb); h[j]   = hb; l[j]   = lb;
        cv2(v1[j], hb, lb); h[4+j] = hb; l[4+j] = lb;
        ss += v0[j] + v1[j];
    }
    return ss;
}

// async global -> LDS, 16B per lane. lds base must be wave-uniform.
static __device__ __forceinline__ void gload16(const float* g, float* lds){
    __builtin_amdgcn_global_load_lds((const __attribute__((address_space(1))) void*)g,
                                     (__attribute__((address_space(3))) void*)lds,
                                     16, 0, 0);
}

// ======================= K1: Gram G = sum_n x x^T ==========================
// Tile: [128 rows][32 cols] f32 in LDS, 9 16B-slots per row (8 data + 1 pad).
// Odd stride-9 spreads fragment b128 reads across bank slots: (row+grp)%8 -> 2-way.
#define GR_NT 18
#define GR_TS 1152          // 16B slots per tile (128*9)
#define GR_TF 4608          // floats per tile

static __device__ __forceinline__ void gram_stage(float* Lt, const float* __restrict__ xb,
                                                  int n0, int tid){
#pragma unroll
    for (int i=0;i<5;i++){
        const int Sbase = i*256 + (tid & ~63);      // wave-uniform slot base
        if (Sbase < GR_TS){
            const int S   = Sbase + (tid & 63);
            const int R   = S / 9;                  // row
            const int grp = S - R*9;                // 16B slot in row
            const int c4  = (grp == 8) ? 0 : grp*4; // pad slot: dup fetch, never read
            gload16(xb + (size_t)R*NHW + n0 + c4, Lt + (size_t)Sbase*4);
        }
    }
}

template<int W>
static __device__ __forceinline__ void gram_work(const float* __restrict__ xb,
        float* __restrict__ Gb, float* __restrict__ sb,
        float* Ls, const int chunk, const int tid){
    const int lane = tid & 63;
    const int l16 = lane & 15, lgi = lane >> 4;
    constexpr int W2 = 2*W;

    f32x4 acc[2][8];
#pragma unroll
    for (int p=0;p<2;p++)
#pragma unroll
      for (int g=0;g<8;g++) acc[p][g] = zero4();
    float ssum[8];
#pragma unroll
    for (int g=0;g<8;g++) ssum[g] = 0.f;

    const int nb = chunk*576;
    gram_stage(Ls, xb, nb, tid);
    __syncthreads();

    int cur = 0;
    for (int t=0; t<GR_NT; ++t){
        if (t+1 < GR_NT) gram_stage(Ls + (cur^1)*GR_TF, xb, nb + (t+1)*32, tid);

        const float* Lb = Ls + cur*GR_TF;
        // A-fragments: rows W2*16.., (W2+1)*16.. (also reused as B rows g=W2,W2+1)
        f32x4 a00 = *(const f32x4*)(Lb + (size_t)(W2*16     + l16)*36 + lgi*8);
        f32x4 a01 = *(const f32x4*)(Lb + (size_t)(W2*16     + l16)*36 + lgi*8 + 4);
        f32x4 a10 = *(const f32x4*)(Lb + (size_t)((W2+1)*16 + l16)*36 + lgi*8);
        f32x4 a11 = *(const f32x4*)(Lb + (size_t)((W2+1)*16 + l16)*36 + lgi*8 + 4);
        short8 hA0, lA0, hA1, lA1;
        const float sA0 = cv8(a00, a01, hA0, lA0);
        const float sA1 = cv8(a10, a11, hA1, lA1);

#pragma unroll
        for (int g=0; g<8; g++){
            short8 hg, lg2;
            float sg;
            if (g == W2)        { hg = hA0; lg2 = lA0; sg = sA0; }
            else if (g == W2+1) { hg = hA1; lg2 = lA1; sg = sA1; }
            else {
                f32x4 b0 = *(const f32x4*)(Lb + (size_t)(g*16 + l16)*36 + lgi*8);
                f32x4 b1 = *(const f32x4*)(Lb + (size_t)(g*16 + l16)*36 + lgi*8 + 4);
                sg = cv8(b0, b1, hg, lg2);
            }
            if (W == 0) ssum[g] += sg;
            acc[0][g] = __builtin_amdgcn_mfma_f32_16x16x32_bf16(hA0, hg,  acc[0][g], 0,0,0);
            acc[0][g] = __builtin_amdgcn_mfma_f32_16x16x32_bf16(hA0, lg2, acc[0][g], 0,0,0);
            acc[0][g] = __builtin_amdgcn_mfma_f32_16x16x32_bf16(lA0, hg,  acc[0][g], 0,0,0);
            acc[1][g] = __builtin_amdgcn_mfma_f32_16x16x32_bf16(hA1, hg,  acc[1][g], 0,0,0);
            acc[1][g] = __builtin_amdgcn_mfma_f32_16x16x32_bf16(hA1, lg2, acc[1][g], 0,0,0);
            acc[1][g] = __builtin_amdgcn_mfma_f32_16x16x32_bf16(lA1, hg,  acc[1][g], 0,0,0);
        }
        __syncthreads();
        cur ^= 1;
    }

    // C/D layout (pass-verified): col = lane&15, row = (lane>>4)*4 + reg
#pragma unroll
    for (int p=0;p<2;p++){
        const int rg = W2 + p;
#pragma unroll
        for (int g=0;g<8;g++){
#pragma unroll
            for (int r=0;r<4;r++){
                atomicAdd(&Gb[(size_t)(rg*16 + lgi*4 + r)*NC + g*16 + l16], acc[p][g][r]);
            }
        }
    }
    if (W == 0){
#pragma unroll
        for (int g=0;g<8;g++){
            float v = ssum[g];
            v += __shfl_xor(v, 16);
            v += __shfl_xor(v, 32);
            if (lane < 16) atomicAdd(&sb[g*16 + lane], v);
        }
    }
}

__global__ __launch_bounds__(256) void k_gram(const float* __restrict__ x,
                                              float* __restrict__ G,
                                              float* __restrict__ svec){
    __shared__ float Ls[2*GR_TF];   // 36 KB
    const int b     = blockIdx.y;
    const int chunk = blockIdx.x;   // 64 chunks * 576 n
    const int tid   = threadIdx.x;
    const int wid   = tid >> 6;
    const float* xb = x + (size_t)b*NC*NHW;
    float* Gb = G + (size_t)b*NC*NC;
    float* sb = svec + b*NC;
    switch (wid){
        case 0: gram_work<0>(xb, Gb, sb, Ls, chunk, tid); break;
        case 1: gram_work<1>(xb, Gb, sb, Ls, chunk, tid); break;
        case 2: gram_work<2>(xb, Gb, sb, Ls, chunk, tid); break;
        default: gram_work<3>(xb, Gb, sb, Ls, chunk, tid); break;
    }
}

// ---- K2: energy = Wq G Wk^T + rank-1 terms; softmax -> A (LDS); t = A bv; R = A Wv ----
__global__ __launch_bounds__(256) void k_energyav(const float* __restrict__ G,
        const float* __restrict__ svec,
        const float* __restrict__ Wq, const float* __restrict__ bq,
        const float* __restrict__ Wk, const float* __restrict__ bk,
        const float* __restrict__ bv, const float* __restrict__ Wv,
        float* __restrict__ R, float* __restrict__ tvec){
    const int b  = blockIdx.y;
    const int d0 = blockIdx.x * 16;
    const int tid = threadIdx.x;
    const int d  = tid & 15;
    const int ec = tid >> 4;

    __shared__ float Ps[16][128];
    __shared__ float Es[16][128];
    __shared__ float red[16][16];
    __shared__ float rowmax[16];
    __shared__ float rowsum[16];
    __shared__ float qs[16];

    const float* Wqrow = Wq + (size_t)(d0 + d)*NC;
    const float* sb = svec + b*NC;
#pragma unroll
    for (int i=0;i<8;i++){
        const int c = ec*8 + i;
        const float* Grow = G + ((size_t)b*NC + c)*NC;
        float a = 0.f;
        for (int c4=0;c4<32;c4++){
            f32x4 g4 = *(const f32x4*)(Grow + c4*4);
            f32x4 w4 = *(const f32x4*)(Wqrow + c4*4);
            a += g4[0]*w4[0] + g4[1]*w4[1] + g4[2]*w4[2] + g4[3]*w4[3];
        }
        Ps[d][c] = a;
    }
    if (ec == 0){
        float a = 0.f;
        for (int c4=0;c4<32;c4++){
            f32x4 w4 = *(const f32x4*)(Wqrow + c4*4);
            f32x4 s4 = *(const f32x4*)(sb + c4*4);
            a += w4[0]*s4[0] + w4[1]*s4[1] + w4[2]*s4[2] + w4[3]*s4[3];
        }
        qs[d] = a;
    }
    __syncthreads();
    const float bqd = bq[d0+d];
#pragma unroll
    for (int i=0;i<8;i++){
        const int e = ec*8 + i;
        const float* Wkrow = Wk + (size_t)e*NC;
        float ea = 0.f, ks = 0.f;
        for (int c4=0;c4<32;c4++){
            f32x4 w4 = *(const f32x4*)(Wkrow + c4*4);
            f32x4 p4 = *(const f32x4*)(&Ps[d][c4*4]);
            f32x4 s4 = *(const f32x4*)(sb + c4*4);
            ea += w4[0]*p4[0]+w4[1]*p4[1]+w4[2]*p4[2]+w4[3]*p4[3];
            ks += w4[0]*s4[0]+w4[1]*s4[1]+w4[2]*s4[2]+w4[3]*s4[3];
        }
        const float bke = bk[e];
        Es[d][e] = ea + bke*qs[d] + bqd*ks + (float)NHW*bqd*bke;
    }
    float m8 = -3.4e38f;
#pragma unroll
    for (int i=0;i<8;i++) m8 = fmaxf(m8, Es[d][ec*8+i]);
    red[d][ec] = m8;
    __syncthreads();
    if (tid < 16){
        float m = red[tid][0];
        for (int j=1;j<16;j++) m = fmaxf(m, red[tid][j]);
        rowmax[tid] = m;
    }
    __syncthreads();
    const float rm = rowmax[d];
    float s8 = 0.f;
#pragma unroll
    for (int i=0;i<8;i++){
        float ex = expf(Es[d][ec*8+i] - rm);
        Es[d][ec*8+i] = ex;
        s8 += ex;
    }
    red[d][ec] = s8;
    __syncthreads();
    if (tid < 16){
        float sm = 0.f;
        for (int j=0;j<16;j++) sm += red[tid][j];
        rowsum[tid] = sm;
    }
    __syncthreads();
    const float inv = 1.f / rowsum[d];
    float ta = 0.f;
#pragma unroll
    for (int i=0;i<8;i++){
        const int e = ec*8 + i;
        float av = Es[d][e] * inv;
        Es[d][e] = av;
        ta += av * bv[e];
    }
    red[d][ec] = ta;
    __syncthreads();
    if (tid < 16){
        float sm = 0.f;
        for (int j=0;j<16;j++) sm += red[tid][j];
        tvec[b*NC + d0 + tid] = sm;
    }
    const int c0 = ec*8;
    float racc[8];
#pragma unroll
    for (int i=0;i<8;i++) racc[i]=0.f;
    for (int e=0;e<NC;e++){
        const float av = Es[d][e];
        const float* wv = Wv + (size_t)e*NC + c0;
        f32x4 w0 = *(const f32x4*)wv;
        f32x4 w1 = *(const f32x4*)(wv+4);
        racc[0]+=av*w0[0]; racc[1]+=av*w0[1]; racc[2]+=av*w0[2]; racc[3]+=av*w0[3];
        racc[4]+=av*w1[0]; racc[5]+=av*w1[1]; racc[6]+=av*w1[2]; racc[7]+=av*w1[3];
    }
    float* Rrow = R + ((size_t)b*NC + d0 + d)*NC + c0;
#pragma unroll
    for (int i=0;i<8;i++) Rrow[i] = racc[i];
}

// ---- K3: M = Wo * R -> bf16 fragment layout Mb; cvec = Wo * t + bo ----
__global__ __launch_bounds__(256) void k_om(const float* __restrict__ R,
        const float* __restrict__ Wo, const float* __restrict__ bo,
        const float* __restrict__ tvec, short* __restrict__ Mb,
        float* __restrict__ cvec){
    const int b = blockIdx.y, o0 = blockIdx.x*16;
    const int tid = threadIdx.x, o = tid&15, cc = tid>>4;
    const int c0 = cc*8;
    const float* Worow = Wo + (size_t)(o0+o)*NC;
    const float* tb = tvec + b*NC;
    float a[8];
#pragma unroll
    for (int i=0;i<8;i++) a[i]=0.f;
    float cv = 0.f;
    for (int dd=0; dd<NC; dd++){
        const float wv = Worow[dd];
        const float* r = R + ((size_t)b*NC + dd)*NC + c0;
        f32x4 r0 = *(const f32x4*)r;
        f32x4 r1 = *(const f32x4*)(r+4);
        a[0]+=wv*r0[0]; a[1]+=wv*r0[1]; a[2]+=wv*r0[2]; a[3]+=wv*r0[3];
        a[4]+=wv*r1[0]; a[5]+=wv*r1[1]; a[6]+=wv*r1[2]; a[7]+=wv*r1[3];
        cv += wv*tb[dd];
    }
    // M[c][m] -> fragment (cg, kstep, lane=lg*16+l16, j): c=cg*16+l16, m=kstep*32+lg*8+j
    const int cfull = o0 + o;
    const int cg = cfull >> 4, l16v = cfull & 15;
    const int kst = c0 >> 5, lgv = (c0 >> 3) & 3;
    const int lanev = lgv*16 + l16v;
    short8 h;
#pragma unroll
    for (int i=0;i<8;i++) h[i] = bfbits(a[i]);
    *(short8*)(Mb + ((((size_t)b*8 + cg)*4 + kst)*64 + lanev)*8) = h;
    if (cc == 0) cvec[b*NC + o0 + o] = cv + bo[o0+o];
}

// ---- K4: out = gamma*(M x + cvec) + x  — x staged [128][128] f32 via global_load_lds ----
__global__ __launch_bounds__(256) void k_final(const float* __restrict__ x,
        const short* __restrict__ Mb, const float* __restrict__ cvec,
        const float* __restrict__ gamma, float* __restrict__ out){
    __shared__ float Xs[NC*128];    // 64 KB: [m][n-n0] row-major
    const int b   = blockIdx.y;
    const int n0  = blockIdx.x * 128;
    const int tid = threadIdx.x;
    const int wid = tid >> 6, lane = tid & 63;
    const int l16 = lane & 15, lgi = lane >> 4;

    const float* xb  = x + (size_t)b*NC*NHW;
    const short* Mbb = Mb + (size_t)b*8*4*64*8;

    // stage: 4096 slots of 16B, fully coalesced (each row = 512B contiguous)
#pragma unroll
    for (int i=0;i<16;i++){
        const int Sbase = i*256 + (tid & ~63);
        const int S = Sbase + (tid & 63);
        const int m = S >> 5, grp = S & 31;
        gload16(xb + (size_t)m*NHW + n0 + grp*4, Xs + (size_t)Sbase*4);
    }
    __syncthreads();

    f32x4 acc[2][8];
#pragma unroll
    for (int t=0;t<2;t++)
#pragma unroll
      for (int g=0;g<8;g++) acc[t][g]=zero4();

#pragma unroll
    for (int ks=0;ks<4;ks++){
        // B-fragments from LDS: m = ks*32 + lgi*8 + j, n = wid*32 + {l16, 16+l16}
        const float* Lk = Xs + (size_t)(ks*32 + lgi*8)*128 + wid*32;
        short8 bf0, bf1;
#pragma unroll
        for (int j=0;j<8;j++){
            bf0[j] = bfbits(Lk[j*128 + l16]);
            bf1[j] = bfbits(Lk[j*128 + 16 + l16]);
        }
#pragma unroll
        for (int cg=0;cg<8;cg++){
            short8 a = *(const short8*)(Mbb + (((size_t)cg*4 + ks)*64 + lane)*8);
            acc[0][cg] = __builtin_amdgcn_mfma_f32_16x16x32_bf16(a, bf0, acc[0][cg], 0,0,0);
            acc[1][cg] = __builtin_amdgcn_mfma_f32_16x16x32_bf16(a, bf1, acc[1][cg], 0,0,0);
        }
    }

    const float gm = gamma[0];
#pragma unroll
    for (int t=0;t<2;t++){
        const int nn = wid*32 + t*16 + l16;
        const int n  = n0 + nn;
#pragma unroll
        for (int cg=0;cg<8;cg++){
#pragma unroll
            for (int r=0;r<4;r++){
                const int c = cg*16 + lgi*4 + r;
                out[((size_t)b*NC + c)*NHW + n] =
                    gm*(acc[t][cg][r] + cvec[b*NC + c]) + Xs[(size_t)c*128 + nn];
            }
        }
    }
}

extern "C" void kernel_launch(void* const* d_in, const int* in_sizes, int n_in,
                              void* d_out, int out_size, void* d_ws, size_t ws_size,
                              hipStream_t stream){
    const float* x     = (const float*)d_in[0];
    const float* Wq    = (const float*)d_in[1];
    const float* bq    = (const float*)d_in[2];
    const float* Wk    = (const float*)d_in[3];
    const float* bk    = (const float*)d_in[4];
    const float* Wv    = (const float*)d_in[5];
    const float* bv    = (const float*)d_in[6];
    const float* Wo    = (const float*)d_in[7];
    const float* bo    = (const float*)d_in[8];
    const float* gamma = (const float*)d_in[9];
    float* out = (float*)d_out;

    float* w  = (float*)d_ws;
    float* G  = w + GOFF;
    float* S  = w + SOFF;
    float* T  = w + TOFF;
    float* R  = w + ROFF;
    float* CV = w + CVOFF;
    short* Mb = (short*)(w + MBOFF);

    // zero atomic-accumulation targets (G and s)
    hipMemsetAsync(G, 0, (size_t)(131072 + 1024)*sizeof(float), stream);

    k_gram    <<<dim3(64,  NB), 256, 0, stream>>>(x, G, S);
    k_energyav<<<dim3(8,   NB), 256, 0, stream>>>(G, S, Wq, bq, Wk, bk, bv, Wv, R, T);
    k_om      <<<dim3(8,   NB), 256, 0, stream>>>(R, Wo, bo, T, Mb, CV);
    k_final   <<<dim3(288, NB), 256, 0, stream>>>(x, Mb, CV, gamma, out);
}